// Round 3
// baseline (480.834 us; speedup 1.0000x reference)
//
#include <hip/hip_runtime.h>
#include <cmath>

namespace {

using f16 = _Float16;
typedef f16 f16x8 __attribute__((ext_vector_type(8)));
typedef float f32x4 __attribute__((ext_vector_type(4)));

constexpr int FE = 1216, FN = 1108, MD = 256, KC = 600;
constexpr int PAIRS = 65536, ROWS = 1024;
constexpr int FNP = 1152;          // FN padded to 18*64
constexpr int KCP = 640;           // KC padded for MFMA tiles

// workspace offsets (float units, all 16B-aligned)
constexpr size_t OFF_XP    = 0;                       // fp32 [1024][256]
constexpr size_t OFF_XPF   = OFF_XP   + 262144;       // f16  [1024][256]
constexpr size_t OFF_XPH   = OFF_XPF  + 131072;       // fp32 [1024][256]
constexpr size_t OFF_S1    = OFF_XPH  + 262144;       // fp32 [65536]
constexpr size_t OFF_S2    = OFF_S1   + 65536;        // fp32 [65536]
constexpr size_t OFF_XF    = OFF_S2   + 65536;        // f16  [1024][256]
constexpr size_t OFF_WER8  = OFF_XF   + 131072;       // f16 prefrag 152*256*8
constexpr size_t OFF_WNR8  = OFF_WER8 + 155648;       // 144*256*8
constexpr size_t OFF_WEV8  = OFF_WNR8 + 147456;       // 32*256*8
constexpr size_t OFF_WHW8  = OFF_WEV8 + 32768;        // 32*256*8
constexpr size_t OFF_WL18  = OFF_WHW8 + 32768;        // 32*256*8
constexpr size_t OFF_WI8   = OFF_WL18 + 32768;        // 32*768*8
constexpr size_t OFF_WH8   = OFF_WI8  + 98304;        // 32*768*8
constexpr size_t OFF_WRO8  = OFF_WH8  + 98304;        // 32*640*8
constexpr size_t OFF_E0H   = OFF_WRO8 + 81920;        // f16 [65536][256]
constexpr size_t OFF_MPREH = OFF_E0H  + 8388608;      // f16 [65536][256]

__device__ __forceinline__ float sigmoidf_(float x) { return 1.0f / (1.0f + expf(-x)); }

__device__ __forceinline__ f16x8 cvt8(const float4& a, const float4& b) {
  f16x8 h;
  h[0]=(f16)a.x; h[1]=(f16)a.y; h[2]=(f16)a.z; h[3]=(f16)a.w;
  h[4]=(f16)b.x; h[5]=(f16)b.y; h[6]=(f16)b.z; h[7]=(f16)b.w;
  return h;
}

// ---------------------------------------------------------------------------
// cast_all: prefragment all weight matrices into f16 MFMA-B layout
// out[(kc*Npad + n)*8 + j] = W[n][koff + kc*8 + j]  (0 outside valid range)
// ---------------------------------------------------------------------------
__global__ __launch_bounds__(256) void cast_all(
    const float* __restrict__ W_er, const float* __restrict__ W_nr,
    const float* __restrict__ Wm,   const float* __restrict__ Wl1,
    const float* __restrict__ Wi,   const float* __restrict__ Wh,
    const float* __restrict__ Wro,
    f16* __restrict__ Wer8, f16* __restrict__ Wnr8, f16* __restrict__ Wev8,
    f16* __restrict__ Whw8, f16* __restrict__ Wl18, f16* __restrict__ Wi8,
    f16* __restrict__ Wh8,  f16* __restrict__ Wro8)
{
  int b = blockIdx.x, t = threadIdx.x;
  const float* W; f16* out; int ldw, koff, K, N, Npad, kc, nb;
  if (b < 152)      { W=W_er; out=Wer8; ldw=FE;  koff=0;   K=FE;  N=256; Npad=256; kc=b;     nb=0; }
  else if (b < 296) { b-=152; W=W_nr; out=Wnr8; ldw=FN;  koff=0;   K=FN;  N=256; Npad=256; kc=b; nb=0; }
  else if (b < 328) { b-=296; W=Wm;   out=Wev8; ldw=512; koff=256; K=256; N=256; Npad=256; kc=b; nb=0; }
  else if (b < 360) { b-=328; W=Wm;   out=Whw8; ldw=512; koff=0;   K=256; N=256; Npad=256; kc=b; nb=0; }
  else if (b < 392) { b-=360; W=Wl1;  out=Wl18; ldw=256; koff=0;   K=256; N=256; Npad=256; kc=b; nb=0; }
  else if (b < 488) { b-=392; W=Wi;   out=Wi8;  ldw=256; koff=0;   K=256; N=768; Npad=768; kc=b&31; nb=(b>>5)*256; }
  else if (b < 584) { b-=488; W=Wh;   out=Wh8;  ldw=256; koff=0;   K=256; N=768; Npad=768; kc=b&31; nb=(b>>5)*256; }
  else              { b-=584; W=Wro;  out=Wro8; ldw=256; koff=0;   K=256; N=600; Npad=640; kc=b&31; nb=(b>>5)*256; }
  int n = nb + t;
  if (n >= Npad) return;
  f16x8 h;
#pragma unroll
  for (int j = 0; j < 8; ++j) {
    int k = kc * 8 + j;
    float v = (k < K && n < N) ? W[(size_t)n * ldw + koff + k] : 0.0f;
    h[j] = (f16)v;
  }
  *reinterpret_cast<f16x8*>(out + ((size_t)kc * Npad + n) * 8) = h;
}

// ---------------------------------------------------------------------------
// E0 GEMM (2-phase dbuf): M=65536, N=256, K=1216. A=ef fp32, B prefrag f16.
// BM=64, 4 waves x 64 cols. Out: E0 f16 (+bias).
// ---------------------------------------------------------------------------
__global__ __launch_bounds__(256) void gemm_e0(
    const float* __restrict__ A, const f16* __restrict__ Bp,
    const float* __restrict__ bias, f16* __restrict__ C)
{
  const int blk = blockIdx.x;
  const int tid = threadIdx.x;
  const int wave = tid >> 6, l = tid & 63;
  const int lo = l & 15, hi = l >> 4;
  const int wcol = wave * 64;
  __shared__ f16 As[2][64][72];
  f32x4 acc[4][4] = {};
  const size_t arow0 = (size_t)blk * 64;
  const int srow = tid >> 2, spart = tid & 3;
  const float* aptr = A + (arow0 + srow) * FE + spart * 16;
  float4 g0, g1, g2, g3;

  // prologue
  g0 = *(const float4*)(aptr + 0); g1 = *(const float4*)(aptr + 4);
  g2 = *(const float4*)(aptr + 8); g3 = *(const float4*)(aptr + 12);
  aptr += 64;
  *reinterpret_cast<f16x8*>(&As[0][srow][spart*16])     = cvt8(g0, g1);
  *reinterpret_cast<f16x8*>(&As[0][srow][spart*16 + 8]) = cvt8(g2, g3);

  for (int t = 0; t < 19; ++t) {
    __syncthreads();
    if (t < 18) {       // issue next chunk's loads early (T14)
      g0 = *(const float4*)(aptr + 0); g1 = *(const float4*)(aptr + 4);
      g2 = *(const float4*)(aptr + 8); g3 = *(const float4*)(aptr + 12);
      aptr += 64;
    }
    const int cur = t & 1;
#pragma unroll
    for (int ks = 0; ks < 2; ++ks) {
      f16x8 af[4], bf[4];
      const int kc = t*8 + ks*4 + hi;
#pragma unroll
      for (int m = 0; m < 4; ++m)
        af[m] = *reinterpret_cast<const f16x8*>(&As[cur][m*16 + lo][ks*32 + hi*8]);
#pragma unroll
      for (int n = 0; n < 4; ++n)
        bf[n] = *reinterpret_cast<const f16x8*>(Bp + ((size_t)kc*256 + (wcol + n*16 + lo)) * 8);
#pragma unroll
      for (int m = 0; m < 4; ++m)
#pragma unroll
        for (int n = 0; n < 4; ++n)
          acc[m][n] = __builtin_amdgcn_mfma_f32_16x16x32_f16(af[m], bf[n], acc[m][n], 0, 0, 0);
    }
    if (t < 18) {       // convert + write AFTER compute (overlap with MFMA)
      *reinterpret_cast<f16x8*>(&As[cur^1][srow][spart*16])     = cvt8(g0, g1);
      *reinterpret_cast<f16x8*>(&As[cur^1][srow][spart*16 + 8]) = cvt8(g2, g3);
    }
  }
#pragma unroll
  for (int m = 0; m < 4; ++m)
#pragma unroll
    for (int n = 0; n < 4; ++n) {
      const int col = wcol + n*16 + lo;
      const float bb = bias[col];
#pragma unroll
      for (int r = 0; r < 4; ++r)
        C[(arow0 + m*16 + hi*4 + r) * 256 + col] = (f16)(acc[m][n][r] + bb);
    }
}

// ---------------------------------------------------------------------------
// Xp + XpH fused: Xp = nf@W_nr^T + b_nr (K=1108 pad 1152), then
// XpH = Xp@W_hw^T (K=256) from an LDS f16 copy of the just-computed tile.
// 16 blocks of 64 rows. Outputs: Xp fp32, Xp f16, XpH fp32.
// ---------------------------------------------------------------------------
__global__ __launch_bounds__(256) void gemm_xp_xph(
    const float* __restrict__ A, const f16* __restrict__ Bnr,
    const float* __restrict__ b_nr, const f16* __restrict__ Bhw,
    float* __restrict__ Xp, f16* __restrict__ Xpf, float* __restrict__ XpH)
{
  const int blk = blockIdx.x;
  const int tid = threadIdx.x;
  const int wave = tid >> 6, l = tid & 63;
  const int lo = l & 15, hi = l >> 4;
  const int wcol = wave * 64;
  __shared__ f16 As[2][64][72];
  __shared__ f16 XpS[64][264];
  f32x4 acc[4][4] = {};
  const size_t arow0 = (size_t)blk * 64;
  const int srow = tid >> 2, spart = tid & 3;
  const float* abase = A + (arow0 + srow) * FN;
  float4 g0, g1, g2, g3;
  const float4 z4 = make_float4(0.f, 0.f, 0.f, 0.f);

#define XP_LOAD(T)                                                          \
  { int kb = (T)*64 + spart*16;                                             \
    g0 = (kb +  4 <= FN) ? *(const float4*)(abase + kb    ) : z4;           \
    g1 = (kb +  8 <= FN) ? *(const float4*)(abase + kb + 4) : z4;           \
    g2 = (kb + 12 <= FN) ? *(const float4*)(abase + kb + 8) : z4;           \
    g3 = (kb + 16 <= FN) ? *(const float4*)(abase + kb +12) : z4; }

  XP_LOAD(0);
  *reinterpret_cast<f16x8*>(&As[0][srow][spart*16])     = cvt8(g0, g1);
  *reinterpret_cast<f16x8*>(&As[0][srow][spart*16 + 8]) = cvt8(g2, g3);

  for (int t = 0; t < 18; ++t) {
    __syncthreads();
    if (t < 17) XP_LOAD(t + 1);
    const int cur = t & 1;
#pragma unroll
    for (int ks = 0; ks < 2; ++ks) {
      f16x8 af[4], bf[4];
      const int kc = t*8 + ks*4 + hi;
#pragma unroll
      for (int m = 0; m < 4; ++m)
        af[m] = *reinterpret_cast<const f16x8*>(&As[cur][m*16 + lo][ks*32 + hi*8]);
#pragma unroll
      for (int n = 0; n < 4; ++n)
        bf[n] = *reinterpret_cast<const f16x8*>(Bnr + ((size_t)kc*256 + (wcol + n*16 + lo)) * 8);
#pragma unroll
      for (int m = 0; m < 4; ++m)
#pragma unroll
        for (int n = 0; n < 4; ++n)
          acc[m][n] = __builtin_amdgcn_mfma_f32_16x16x32_f16(af[m], bf[n], acc[m][n], 0, 0, 0);
    }
    if (t < 17) {
      *reinterpret_cast<f16x8*>(&As[cur^1][srow][spart*16])     = cvt8(g0, g1);
      *reinterpret_cast<f16x8*>(&As[cur^1][srow][spart*16 + 8]) = cvt8(g2, g3);
    }
  }
#undef XP_LOAD
  // epilogue 1: Xp fp32 + f16 + LDS tile
#pragma unroll
  for (int m = 0; m < 4; ++m)
#pragma unroll
    for (int n = 0; n < 4; ++n) {
      const int col = wcol + n*16 + lo;
      const float bb = b_nr[col];
#pragma unroll
      for (int r = 0; r < 4; ++r) {
        const int rl = m*16 + hi*4 + r;
        float v = acc[m][n][r] + bb;
        Xp[(arow0 + rl) * 256 + col] = v;
        f16 hv = (f16)v;
        Xpf[(arow0 + rl) * 256 + col] = hv;
        XpS[rl][col] = hv;
      }
    }
  __syncthreads();
  // phase 2: XpH = XpS @ W_hw^T
  f32x4 acch[4][4] = {};
  for (int t = 0; t < 4; ++t) {
#pragma unroll
    for (int ks = 0; ks < 2; ++ks) {
      f16x8 af[4], bf[4];
      const int kc = t*8 + ks*4 + hi;
#pragma unroll
      for (int m = 0; m < 4; ++m)
        af[m] = *reinterpret_cast<const f16x8*>(&XpS[m*16 + lo][t*64 + ks*32 + hi*8]);
#pragma unroll
      for (int n = 0; n < 4; ++n)
        bf[n] = *reinterpret_cast<const f16x8*>(Bhw + ((size_t)kc*256 + (wcol + n*16 + lo)) * 8);
#pragma unroll
      for (int m = 0; m < 4; ++m)
#pragma unroll
        for (int n = 0; n < 4; ++n)
          acch[m][n] = __builtin_amdgcn_mfma_f32_16x16x32_f16(af[m], bf[n], acch[m][n], 0, 0, 0);
    }
  }
#pragma unroll
  for (int m = 0; m < 4; ++m)
#pragma unroll
    for (int n = 0; n < 4; ++n) {
      const int col = wcol + n*16 + lo;
#pragma unroll
      for (int r = 0; r < 4; ++r)
        XpH[(arow0 + m*16 + hi*4 + r) * 256 + col] = acch[m][n][r];
    }
}

// ---------------------------------------------------------------------------
// Fused score-1 + Mpre: one E0 A-tile feeds two GEMMs (Wl1 -> S1, Wev -> Mpre)
// ---------------------------------------------------------------------------
__global__ __launch_bounds__(256) void s1_mpre(
    const f16* __restrict__ E0h, const f16* __restrict__ Bl1,
    const f16* __restrict__ Bev, const float* __restrict__ bl1,
    const float* __restrict__ Wl2, const float* __restrict__ bl2,
    const float* __restrict__ XpH, const float* __restrict__ bm,
    float* __restrict__ S1, f16* __restrict__ Mpreh)
{
  const int blk = blockIdx.x;
  const int tid = threadIdx.x;
  const int wave = tid >> 6, l = tid & 63;
  const int lo = l & 15, hi = l >> 4;
  const int wcol = wave * 64;
  __shared__ f16 As[2][64][72];
  __shared__ float red[64][4];
  f32x4 accS[4][4] = {}, accM[4][4] = {};
  const size_t arow0 = (size_t)blk * 64;
  const int rr0 = tid >> 3, part = tid & 7;   // rows 0..31 (+32), 8 parts
  f16x8 ga, gb;

#define SM_LOAD(T)                                                            \
  { ga = *reinterpret_cast<const f16x8*>(E0h + (arow0 + rr0)*256 + (T)*64 + part*8);      \
    gb = *reinterpret_cast<const f16x8*>(E0h + (arow0 + rr0 + 32)*256 + (T)*64 + part*8); }
#define SM_WRITE(BUF)                                                         \
  { *reinterpret_cast<f16x8*>(&As[BUF][rr0][part*8]) = ga;                    \
    *reinterpret_cast<f16x8*>(&As[BUF][rr0 + 32][part*8]) = gb; }

  SM_LOAD(0); SM_WRITE(0);
  for (int t = 0; t < 4; ++t) {
    __syncthreads();
    if (t < 3) SM_LOAD(t + 1);
    const int cur = t & 1;
#pragma unroll
    for (int ks = 0; ks < 2; ++ks) {
      f16x8 af[4], bfS[4], bfM[4];
      const int kc = t*8 + ks*4 + hi;
#pragma unroll
      for (int m = 0; m < 4; ++m)
        af[m] = *reinterpret_cast<const f16x8*>(&As[cur][m*16 + lo][ks*32 + hi*8]);
#pragma unroll
      for (int n = 0; n < 4; ++n) {
        bfS[n] = *reinterpret_cast<const f16x8*>(Bl1 + ((size_t)kc*256 + (wcol + n*16 + lo)) * 8);
        bfM[n] = *reinterpret_cast<const f16x8*>(Bev + ((size_t)kc*256 + (wcol + n*16 + lo)) * 8);
      }
#pragma unroll
      for (int m = 0; m < 4; ++m)
#pragma unroll
        for (int n = 0; n < 4; ++n) {
          accS[m][n] = __builtin_amdgcn_mfma_f32_16x16x32_f16(af[m], bfS[n], accS[m][n], 0, 0, 0);
          accM[m][n] = __builtin_amdgcn_mfma_f32_16x16x32_f16(af[m], bfM[n], accM[m][n], 0, 0, 0);
        }
    }
    if (t < 3) SM_WRITE(cur ^ 1);
  }
#undef SM_LOAD
#undef SM_WRITE
  // epilogue S1: row-reduce Wl2 . relu(accS + bl1)
#pragma unroll
  for (int m = 0; m < 4; ++m) {
#pragma unroll
    for (int r = 0; r < 4; ++r) {
      float p = 0.f;
#pragma unroll
      for (int n = 0; n < 4; ++n) {
        const int col = wcol + n*16 + lo;
        p += Wl2[col] * fmaxf(accS[m][n][r] + bl1[col], 0.0f);
      }
      p += __shfl_xor(p, 1); p += __shfl_xor(p, 2);
      p += __shfl_xor(p, 4); p += __shfl_xor(p, 8);
      if (lo == 0) red[m*16 + hi*4 + r][wave] = p;
    }
  }
  // epilogue Mpre
  const int rxb = (blk >> 6) * 64;
#pragma unroll
  for (int m = 0; m < 4; ++m)
#pragma unroll
    for (int n = 0; n < 4; ++n) {
      const int col = wcol + n*16 + lo;
      const float bb = bm[col];
#pragma unroll
      for (int r = 0; r < 4; ++r) {
        const int rl = m*16 + hi*4 + r;
        float v = accM[m][n][r] + XpH[(size_t)(rxb + rl)*256 + col] + bb;
        Mpreh[(arow0 + rl)*256 + col] = (f16)fmaxf(v, 0.0f);
      }
    }
  __syncthreads();
  if (tid < 64)
    S1[arow0 + tid] = sigmoidf_(bl2[0] + red[tid][0] + red[tid][1] + red[tid][2] + red[tid][3]);
}

// ---------------------------------------------------------------------------
// Score pass 2: A-rows = Mpre[b,rr,v]*S1[b,rr,v] (transposed gather);
// out: adj[b,v,w]=A2, S2=sigmoid(A2)
// ---------------------------------------------------------------------------
__global__ __launch_bounds__(256) void attn2(
    const f16* __restrict__ Mpreh, const float* __restrict__ S1,
    const f16* __restrict__ Bl1, const float* __restrict__ bl1,
    const float* __restrict__ Wl2, const float* __restrict__ bl2,
    float* __restrict__ S2, float* __restrict__ adj)
{
  const int blk = blockIdx.x;
  const int b = blk >> 6, v = blk & 63;
  const int tid = threadIdx.x;
  const int wave = tid >> 6, l = tid & 63;
  const int lo = l & 15, hi = l >> 4;
  const int wcol = wave * 64;
  __shared__ f16 As[2][64][72];
  __shared__ float red[64][4];
  __shared__ float s1s[64];
  f32x4 acc[4][4] = {};
  const int rr0 = tid >> 3, part = tid & 7;
  const size_t pbase = (size_t)b * 4096 + v;
  f16x8 ga, gb;

  if (tid < 64) s1s[tid] = S1[pbase + (size_t)tid * 64];
  __syncthreads();

#define A2_LOAD(T)                                                              \
  { ga = *reinterpret_cast<const f16x8*>(Mpreh + (pbase + (size_t)rr0*64)*256 + (T)*64 + part*8);     \
    gb = *reinterpret_cast<const f16x8*>(Mpreh + (pbase + (size_t)(rr0+32)*64)*256 + (T)*64 + part*8); }
#define A2_WRITE(BUF)                                                           \
  { f16 sa = (f16)s1s[rr0], sb = (f16)s1s[rr0 + 32];                            \
    f16x8 ha = ga, hb = gb;                                                     \
    _Pragma("unroll") for (int j = 0; j < 8; ++j) { ha[j] *= sa; hb[j] *= sb; } \
    *reinterpret_cast<f16x8*>(&As[BUF][rr0][part*8]) = ha;                      \
    *reinterpret_cast<f16x8*>(&As[BUF][rr0 + 32][part*8]) = hb; }

  A2_LOAD(0); A2_WRITE(0);
  for (int t = 0; t < 4; ++t) {
    __syncthreads();
    if (t < 3) A2_LOAD(t + 1);
    const int cur = t & 1;
#pragma unroll
    for (int ks = 0; ks < 2; ++ks) {
      f16x8 af[4], bf[4];
      const int kc = t*8 + ks*4 + hi;
#pragma unroll
      for (int m = 0; m < 4; ++m)
        af[m] = *reinterpret_cast<const f16x8*>(&As[cur][m*16 + lo][ks*32 + hi*8]);
#pragma unroll
      for (int n = 0; n < 4; ++n)
        bf[n] = *reinterpret_cast<const f16x8*>(Bl1 + ((size_t)kc*256 + (wcol + n*16 + lo)) * 8);
#pragma unroll
      for (int m = 0; m < 4; ++m)
#pragma unroll
        for (int n = 0; n < 4; ++n)
          acc[m][n] = __builtin_amdgcn_mfma_f32_16x16x32_f16(af[m], bf[n], acc[m][n], 0, 0, 0);
    }
    if (t < 3) A2_WRITE(cur ^ 1);
  }
#undef A2_LOAD
#undef A2_WRITE
#pragma unroll
  for (int m = 0; m < 4; ++m) {
#pragma unroll
    for (int r = 0; r < 4; ++r) {
      float p = 0.f;
#pragma unroll
      for (int n = 0; n < 4; ++n) {
        const int col = wcol + n*16 + lo;
        p += Wl2[col] * fmaxf(acc[m][n][r] + bl1[col], 0.0f);
      }
      p += __shfl_xor(p, 1); p += __shfl_xor(p, 2);
      p += __shfl_xor(p, 4); p += __shfl_xor(p, 8);
      if (lo == 0) red[m*16 + hi*4 + r][wave] = p;
    }
  }
  __syncthreads();
  if (tid < 64) {
    float s = bl2[0] + red[tid][0] + red[tid][1] + red[tid][2] + red[tid][3];
    size_t oi = (size_t)b*4096 + v*64 + tid;
    adj[oi] = s;
    S2[oi] = sigmoidf_(s);
  }
}

// x[bv][c] = sum_w Mpre[bv*64+w][c] * S2[bv*64+w]  -> f16
__global__ __launch_bounds__(256) void msum_kernel(
    const f16* __restrict__ Mpre, const float* __restrict__ S2,
    f16* __restrict__ x)
{
  const int bv = blockIdx.x;
  const int c = threadIdx.x;
  float acc = 0.f;
#pragma unroll 8
  for (int w = 0; w < 64; ++w)
    acc += (float)Mpre[((size_t)bv * 64 + w) * 256 + c] * S2[bv * 64 + w];
  x[(size_t)bv * 256 + c] = (f16)acc;
}

// ---------------------------------------------------------------------------
// Fused GRU + labels: 16 blocks of 64 rows.
// gates: acc = x@Wi_g^T + Xp@Wh_g^T (C-in accumulation); GRU elementwise;
// labels = h_new@Wro^T + bro (N padded to 640).
// ---------------------------------------------------------------------------
__global__ __launch_bounds__(256) void gru_labels(
    const f16* __restrict__ xf, const f16* __restrict__ Xpf,
    const float* __restrict__ Xp,
    const f16* __restrict__ Wi8, const f16* __restrict__ Wh8,
    const f16* __restrict__ Wro8,
    const float* __restrict__ bi, const float* __restrict__ bh,
    const float* __restrict__ bro, float* __restrict__ labels)
{
  const int b = blockIdx.x;
  const int tid = threadIdx.x;
  const int wave = tid >> 6, l = tid & 63;
  const int lo = l & 15, hi = l >> 4;
  const int wcol = wave * 64;
  __shared__ f16 xS[64][264];
  __shared__ f16 pS[64][264];
  __shared__ f16 hS[64][264];
  const size_t arow0 = (size_t)b * 64;

#pragma unroll
  for (int i = 0; i < 8; ++i) {            // 2048 f16x8 total, 256 thr
    int idx = i * 256 + tid;
    int rr = idx >> 5, part = idx & 31;
    *reinterpret_cast<f16x8*>(&xS[rr][part*8]) =
        *reinterpret_cast<const f16x8*>(xf + (arow0 + rr)*256 + part*8);
    *reinterpret_cast<f16x8*>(&pS[rr][part*8]) =
        *reinterpret_cast<const f16x8*>(Xpf + (arow0 + rr)*256 + part*8);
  }
  __syncthreads();

  float rg[4][4][4], zg[4][4][4];
#pragma unroll
  for (int g = 0; g < 2; ++g) {
    f32x4 acc[4][4] = {};
    for (int t = 0; t < 4; ++t) {
#pragma unroll
      for (int ks = 0; ks < 2; ++ks) {
        f16x8 ax[4], ap[4], bI[4], bH[4];
        const int kc = t*8 + ks*4 + hi;
#pragma unroll
        for (int m = 0; m < 4; ++m) {
          ax[m] = *reinterpret_cast<const f16x8*>(&xS[m*16 + lo][t*64 + ks*32 + hi*8]);
          ap[m] = *reinterpret_cast<const f16x8*>(&pS[m*16 + lo][t*64 + ks*32 + hi*8]);
        }
#pragma unroll
        for (int n = 0; n < 4; ++n) {
          const int gcol = g*256 + wcol + n*16 + lo;
          bI[n] = *reinterpret_cast<const f16x8*>(Wi8 + ((size_t)kc*768 + gcol) * 8);
          bH[n] = *reinterpret_cast<const f16x8*>(Wh8 + ((size_t)kc*768 + gcol) * 8);
        }
#pragma unroll
        for (int m = 0; m < 4; ++m)
#pragma unroll
          for (int n = 0; n < 4; ++n) {
            acc[m][n] = __builtin_amdgcn_mfma_f32_16x16x32_f16(ax[m], bI[n], acc[m][n], 0, 0, 0);
            acc[m][n] = __builtin_amdgcn_mfma_f32_16x16x32_f16(ap[m], bH[n], acc[m][n], 0, 0, 0);
          }
      }
    }
#pragma unroll
    for (int m = 0; m < 4; ++m)
#pragma unroll
      for (int n = 0; n < 4; ++n) {
        const int gcol = g*256 + wcol + n*16 + lo;
        const float bb = bi[gcol] + bh[gcol];
#pragma unroll
        for (int r = 0; r < 4; ++r) {
          float s = sigmoidf_(acc[m][n][r] + bb);
          if (g == 0) rg[m][n][r] = s; else zg[m][n][r] = s;
        }
      }
  }
  // n-gate (separate i/h accs) + GRU combine
  {
    f32x4 aI[4][4] = {}, aH[4][4] = {};
    for (int t = 0; t < 4; ++t) {
#pragma unroll
      for (int ks = 0; ks < 2; ++ks) {
        f16x8 ax[4], ap[4], bI[4], bH[4];
        const int kc = t*8 + ks*4 + hi;
#pragma unroll
        for (int m = 0; m < 4; ++m) {
          ax[m] = *reinterpret_cast<const f16x8*>(&xS[m*16 + lo][t*64 + ks*32 + hi*8]);
          ap[m] = *reinterpret_cast<const f16x8*>(&pS[m*16 + lo][t*64 + ks*32 + hi*8]);
        }
#pragma unroll
        for (int n = 0; n < 4; ++n) {
          const int gcol = 512 + wcol + n*16 + lo;
          bI[n] = *reinterpret_cast<const f16x8*>(Wi8 + ((size_t)kc*768 + gcol) * 8);
          bH[n] = *reinterpret_cast<const f16x8*>(Wh8 + ((size_t)kc*768 + gcol) * 8);
        }
#pragma unroll
        for (int m = 0; m < 4; ++m)
#pragma unroll
          for (int n = 0; n < 4; ++n) {
            aI[m][n] = __builtin_amdgcn_mfma_f32_16x16x32_f16(ax[m], bI[n], aI[m][n], 0, 0, 0);
            aH[m][n] = __builtin_amdgcn_mfma_f32_16x16x32_f16(ap[m], bH[n], aH[m][n], 0, 0, 0);
          }
      }
    }
#pragma unroll
    for (int m = 0; m < 4; ++m)
#pragma unroll
      for (int n = 0; n < 4; ++n) {
        const int col = wcol + n*16 + lo;
        const int gcol = 512 + col;
        const float bbi = bi[gcol], bbh = bh[gcol];
#pragma unroll
        for (int r = 0; r < 4; ++r) {
          const int rl = m*16 + hi*4 + r;
          float nn = tanhf(aI[m][n][r] + bbi + rg[m][n][r] * (aH[m][n][r] + bbh));
          float hv = Xp[(arow0 + rl)*256 + col];
          float hnew = (1.0f - zg[m][n][r]) * nn + zg[m][n][r] * hv;
          hS[rl][col] = (f16)hnew;
        }
      }
  }
  __syncthreads();
  // labels = hS @ Wro^T + bro   (cols: wave*160 + 10 frags)
  {
    f32x4 aL[4][10] = {};
    const int wc2 = wave * 160;
    for (int t = 0; t < 4; ++t) {
#pragma unroll
      for (int ks = 0; ks < 2; ++ks) {
        f16x8 af[4], bf[10];
        const int kc = t*8 + ks*4 + hi;
#pragma unroll
        for (int m = 0; m < 4; ++m)
          af[m] = *reinterpret_cast<const f16x8*>(&hS[m*16 + lo][t*64 + ks*32 + hi*8]);
#pragma unroll
        for (int n = 0; n < 10; ++n)
          bf[n] = *reinterpret_cast<const f16x8*>(Wro8 + ((size_t)kc*KCP + (wc2 + n*16 + lo)) * 8);
#pragma unroll
        for (int m = 0; m < 4; ++m)
#pragma unroll
          for (int n = 0; n < 10; ++n)
            aL[m][n] = __builtin_amdgcn_mfma_f32_16x16x32_f16(af[m], bf[n], aL[m][n], 0, 0, 0);
      }
    }
#pragma unroll
    for (int m = 0; m < 4; ++m)
#pragma unroll
      for (int n = 0; n < 10; ++n) {
        const int col = wc2 + n*16 + lo;
        if (col < KC) {
          const float bb = bro[col];
#pragma unroll
          for (int r = 0; r < 4; ++r)
            labels[(arow0 + m*16 + hi*4 + r)*(size_t)KC + col] = aL[m][n][r] + bb;
        }
      }
  }
}

} // namespace

extern "C" void kernel_launch(void* const* d_in, const int* in_sizes, int n_in,
                              void* d_out, int out_size, void* d_ws, size_t ws_size,
                              hipStream_t stream)
{
  const float* ef   = (const float*)d_in[0];
  const float* nf   = (const float*)d_in[1];
  const float* W_er = (const float*)d_in[7];
  const float* b_er = (const float*)d_in[8];
  const float* W_nr = (const float*)d_in[9];
  const float* b_nr = (const float*)d_in[10];
  const float* Wl1  = (const float*)d_in[11];
  const float* bl1  = (const float*)d_in[12];
  const float* Wl2  = (const float*)d_in[13];
  const float* bl2  = (const float*)d_in[14];
  const float* Wm   = (const float*)d_in[15];
  const float* bm   = (const float*)d_in[16];
  const float* Wi   = (const float*)d_in[17];
  const float* bi   = (const float*)d_in[18];
  const float* Wh   = (const float*)d_in[19];
  const float* bh   = (const float*)d_in[20];
  const float* Wro  = (const float*)d_in[21];
  const float* bro  = (const float*)d_in[22];

  float* ws = (float*)d_ws;
  float* Xp    = ws + OFF_XP;
  f16*   Xpf   = (f16*)(ws + OFF_XPF);
  float* XpH   = ws + OFF_XPH;
  float* S1    = ws + OFF_S1;
  float* S2    = ws + OFF_S2;
  f16*   xf    = (f16*)(ws + OFF_XF);
  f16*   Wer8  = (f16*)(ws + OFF_WER8);
  f16*   Wnr8  = (f16*)(ws + OFF_WNR8);
  f16*   Wev8  = (f16*)(ws + OFF_WEV8);
  f16*   Whw8  = (f16*)(ws + OFF_WHW8);
  f16*   Wl18  = (f16*)(ws + OFF_WL18);
  f16*   Wi8   = (f16*)(ws + OFF_WI8);
  f16*   Wh8   = (f16*)(ws + OFF_WH8);
  f16*   Wro8  = (f16*)(ws + OFF_WRO8);
  f16*   E0h   = (f16*)(ws + OFF_E0H);
  f16*   Mpreh = (f16*)(ws + OFF_MPREH);
  float* adj    = (float*)d_out;
  float* labels = (float*)d_out + PAIRS;

  dim3 blk(256);

  cast_all<<<dim3(680), blk, 0, stream>>>(W_er, W_nr, Wm, Wl1, Wi, Wh, Wro,
                                          Wer8, Wnr8, Wev8, Whw8, Wl18, Wi8, Wh8, Wro8);
  gemm_xp_xph<<<dim3(16), blk, 0, stream>>>(nf, Wnr8, b_nr, Whw8, Xp, Xpf, XpH);
  gemm_e0<<<dim3(PAIRS / 64), blk, 0, stream>>>(ef, Wer8, b_er, E0h);
  s1_mpre<<<dim3(PAIRS / 64), blk, 0, stream>>>(E0h, Wl18, Wev8, bl1, Wl2, bl2,
                                                XpH, bm, S1, Mpreh);
  attn2<<<dim3(PAIRS / 64), blk, 0, stream>>>(Mpreh, S1, Wl18, bl1, Wl2, bl2,
                                              S2, adj);
  msum_kernel<<<dim3(ROWS), blk, 0, stream>>>(Mpreh, S2, xf);
  gru_labels<<<dim3(16), blk, 0, stream>>>(xf, Xpf, Xp, Wi8, Wh8, Wro8,
                                           bi, bh, bro, labels);
}

// Round 4
// 331.987 us; speedup vs baseline: 1.4483x; 1.4483x over previous
//
#include <hip/hip_runtime.h>
#include <cmath>

namespace {

using f16 = _Float16;
typedef f16 f16x8 __attribute__((ext_vector_type(8)));
typedef float f32x4 __attribute__((ext_vector_type(4)));

constexpr int FE = 1216, FN = 1108, MD = 256, KC = 600;
constexpr int PAIRS = 65536, ROWS = 1024;

// workspace offsets (float units, all 16B-aligned)
constexpr size_t OFF_XP    = 0;                       // fp32 [1024][256]
constexpr size_t OFF_XPF   = OFF_XP   + 262144;       // f16  [1024][256]
constexpr size_t OFF_XPH   = OFF_XPF  + 131072;       // fp32 [1024][256]
constexpr size_t OFF_S1    = OFF_XPH  + 262144;       // fp32 [65536]
constexpr size_t OFF_S2    = OFF_S1   + 65536;        // fp32 [65536]
constexpr size_t OFF_XF    = OFF_S2   + 65536;        // f16  [1024][256]
constexpr size_t OFF_GI    = OFF_XF   + 131072;       // fp32 [1024][768]
constexpr size_t OFF_GH    = OFF_GI   + 786432;       // fp32 [1024][768]
constexpr size_t OFF_HNF   = OFF_GH   + 786432;       // f16  [1024][256]
constexpr size_t OFF_WER8  = OFF_HNF  + 131072;       // f16 prefrag 152*256*8
constexpr size_t OFF_WNR8  = OFF_WER8 + 155648;       // 144*256*8
constexpr size_t OFF_WEV8  = OFF_WNR8 + 147456;       // 32*256*8
constexpr size_t OFF_WHW8  = OFF_WEV8 + 32768;        // 32*256*8
constexpr size_t OFF_WL18  = OFF_WHW8 + 32768;        // 32*256*8
constexpr size_t OFF_WI8   = OFF_WL18 + 32768;        // 32*768*8
constexpr size_t OFF_WH8   = OFF_WI8  + 98304;        // 32*768*8
constexpr size_t OFF_WRO8  = OFF_WH8  + 98304;        // 32*768*8 (KC pad 768)
constexpr size_t OFF_E0H   = OFF_WRO8 + 98304;        // f16 [65536][256]
constexpr size_t OFF_MPREH = OFF_E0H  + 8388608;      // f16 [65536][256]

__device__ __forceinline__ float sigmoidf_(float x) { return 1.0f / (1.0f + expf(-x)); }

__device__ __forceinline__ f16x8 cvt8(const float4& a, const float4& b) {
  f16x8 h;
  h[0]=(f16)a.x; h[1]=(f16)a.y; h[2]=(f16)a.z; h[3]=(f16)a.w;
  h[4]=(f16)b.x; h[5]=(f16)b.y; h[6]=(f16)b.z; h[7]=(f16)b.w;
  return h;
}

// ---------------------------------------------------------------------------
// cast_all: prefragment all weight matrices into f16 MFMA-B layout
// out[(kc*Npad + n)*8 + j] = W[n][koff + kc*8 + j]  (0 outside valid range)
// ---------------------------------------------------------------------------
__global__ __launch_bounds__(256) void cast_all(
    const float* __restrict__ W_er, const float* __restrict__ W_nr,
    const float* __restrict__ Wm,   const float* __restrict__ Wl1,
    const float* __restrict__ Wi,   const float* __restrict__ Wh,
    const float* __restrict__ Wro,
    f16* __restrict__ Wer8, f16* __restrict__ Wnr8, f16* __restrict__ Wev8,
    f16* __restrict__ Whw8, f16* __restrict__ Wl18, f16* __restrict__ Wi8,
    f16* __restrict__ Wh8,  f16* __restrict__ Wro8)
{
  int b = blockIdx.x, t = threadIdx.x;
  const float* W; f16* out; int ldw, koff, K, N, Npad, kc, nb;
  if (b < 152)      { W=W_er; out=Wer8; ldw=FE;  koff=0;   K=FE;  N=256; Npad=256; kc=b;     nb=0; }
  else if (b < 296) { b-=152; W=W_nr; out=Wnr8; ldw=FN;  koff=0;   K=FN;  N=256; Npad=256; kc=b; nb=0; }
  else if (b < 328) { b-=296; W=Wm;   out=Wev8; ldw=512; koff=256; K=256; N=256; Npad=256; kc=b; nb=0; }
  else if (b < 360) { b-=328; W=Wm;   out=Whw8; ldw=512; koff=0;   K=256; N=256; Npad=256; kc=b; nb=0; }
  else if (b < 392) { b-=360; W=Wl1;  out=Wl18; ldw=256; koff=0;   K=256; N=256; Npad=256; kc=b; nb=0; }
  else if (b < 488) { b-=392; W=Wi;   out=Wi8;  ldw=256; koff=0;   K=256; N=768; Npad=768; kc=b&31; nb=(b>>5)*256; }
  else if (b < 584) { b-=488; W=Wh;   out=Wh8;  ldw=256; koff=0;   K=256; N=768; Npad=768; kc=b&31; nb=(b>>5)*256; }
  else              { b-=584; W=Wro;  out=Wro8; ldw=256; koff=0;   K=256; N=600; Npad=768; kc=b&31; nb=(b>>5)*256; }
  int n = nb + t;
  if (n >= Npad) return;
  f16x8 h;
#pragma unroll
  for (int j = 0; j < 8; ++j) {
    int k = kc * 8 + j;
    float v = (k < K && n < N) ? W[(size_t)n * ldw + koff + k] : 0.0f;
    h[j] = (f16)v;
  }
  *reinterpret_cast<f16x8*>(out + ((size_t)kc * Npad + n) * 8) = h;
}

// ---------------------------------------------------------------------------
// E0 GEMM (2-phase dbuf): M=65536, N=256, K=1216. A=ef fp32, B prefrag f16.
// ---------------------------------------------------------------------------
__global__ __launch_bounds__(256) void gemm_e0(
    const float* __restrict__ A, const f16* __restrict__ Bp,
    const float* __restrict__ bias, f16* __restrict__ C)
{
  const int blk = blockIdx.x;
  const int tid = threadIdx.x;
  const int wave = tid >> 6, l = tid & 63;
  const int lo = l & 15, hi = l >> 4;
  const int wcol = wave * 64;
  __shared__ f16 As[2][64][72];
  f32x4 acc[4][4] = {};
  const size_t arow0 = (size_t)blk * 64;
  const int srow = tid >> 2, spart = tid & 3;
  const float* aptr = A + (arow0 + srow) * FE + spart * 16;
  float4 g0, g1, g2, g3;

  g0 = *(const float4*)(aptr + 0); g1 = *(const float4*)(aptr + 4);
  g2 = *(const float4*)(aptr + 8); g3 = *(const float4*)(aptr + 12);
  aptr += 64;
  *reinterpret_cast<f16x8*>(&As[0][srow][spart*16])     = cvt8(g0, g1);
  *reinterpret_cast<f16x8*>(&As[0][srow][spart*16 + 8]) = cvt8(g2, g3);

  for (int t = 0; t < 19; ++t) {
    __syncthreads();
    if (t < 18) {
      g0 = *(const float4*)(aptr + 0); g1 = *(const float4*)(aptr + 4);
      g2 = *(const float4*)(aptr + 8); g3 = *(const float4*)(aptr + 12);
      aptr += 64;
    }
    const int cur = t & 1;
#pragma unroll
    for (int ks = 0; ks < 2; ++ks) {
      f16x8 af[4], bf[4];
      const int kc = t*8 + ks*4 + hi;
#pragma unroll
      for (int m = 0; m < 4; ++m)
        af[m] = *reinterpret_cast<const f16x8*>(&As[cur][m*16 + lo][ks*32 + hi*8]);
#pragma unroll
      for (int n = 0; n < 4; ++n)
        bf[n] = *reinterpret_cast<const f16x8*>(Bp + ((size_t)kc*256 + (wcol + n*16 + lo)) * 8);
#pragma unroll
      for (int m = 0; m < 4; ++m)
#pragma unroll
        for (int n = 0; n < 4; ++n)
          acc[m][n] = __builtin_amdgcn_mfma_f32_16x16x32_f16(af[m], bf[n], acc[m][n], 0, 0, 0);
    }
    if (t < 18) {
      *reinterpret_cast<f16x8*>(&As[cur^1][srow][spart*16])     = cvt8(g0, g1);
      *reinterpret_cast<f16x8*>(&As[cur^1][srow][spart*16 + 8]) = cvt8(g2, g3);
    }
  }
#pragma unroll
  for (int m = 0; m < 4; ++m)
#pragma unroll
    for (int n = 0; n < 4; ++n) {
      const int col = wcol + n*16 + lo;
      const float bb = bias[col];
#pragma unroll
      for (int r = 0; r < 4; ++r)
        C[(arow0 + m*16 + hi*4 + r) * 256 + col] = (f16)(acc[m][n][r] + bb);
    }
}

// ---------------------------------------------------------------------------
// Xp GEMM: Xp = nf@W_nr^T + b_nr (K=1108 pad 1152). Out fp32 + f16.
// ---------------------------------------------------------------------------
__global__ __launch_bounds__(256) void gemm_xp(
    const float* __restrict__ A, const f16* __restrict__ Bnr,
    const float* __restrict__ b_nr,
    float* __restrict__ Xp, f16* __restrict__ Xpf)
{
  const int blk = blockIdx.x;
  const int tid = threadIdx.x;
  const int wave = tid >> 6, l = tid & 63;
  const int lo = l & 15, hi = l >> 4;
  const int wcol = wave * 64;
  __shared__ f16 As[2][64][72];
  f32x4 acc[4][4] = {};
  const size_t arow0 = (size_t)blk * 64;
  const int srow = tid >> 2, spart = tid & 3;
  const float* abase = A + (arow0 + srow) * FN;
  float4 g0, g1, g2, g3;
  const float4 z4 = make_float4(0.f, 0.f, 0.f, 0.f);

#define XP_LOAD(T)                                                          \
  { int kb = (T)*64 + spart*16;                                             \
    g0 = (kb +  4 <= FN) ? *(const float4*)(abase + kb    ) : z4;           \
    g1 = (kb +  8 <= FN) ? *(const float4*)(abase + kb + 4) : z4;           \
    g2 = (kb + 12 <= FN) ? *(const float4*)(abase + kb + 8) : z4;           \
    g3 = (kb + 16 <= FN) ? *(const float4*)(abase + kb +12) : z4; }

  XP_LOAD(0);
  *reinterpret_cast<f16x8*>(&As[0][srow][spart*16])     = cvt8(g0, g1);
  *reinterpret_cast<f16x8*>(&As[0][srow][spart*16 + 8]) = cvt8(g2, g3);

  for (int t = 0; t < 18; ++t) {
    __syncthreads();
    if (t < 17) XP_LOAD(t + 1);
    const int cur = t & 1;
#pragma unroll
    for (int ks = 0; ks < 2; ++ks) {
      f16x8 af[4], bf[4];
      const int kc = t*8 + ks*4 + hi;
#pragma unroll
      for (int m = 0; m < 4; ++m)
        af[m] = *reinterpret_cast<const f16x8*>(&As[cur][m*16 + lo][ks*32 + hi*8]);
#pragma unroll
      for (int n = 0; n < 4; ++n)
        bf[n] = *reinterpret_cast<const f16x8*>(Bnr + ((size_t)kc*256 + (wcol + n*16 + lo)) * 8);
#pragma unroll
      for (int m = 0; m < 4; ++m)
#pragma unroll
        for (int n = 0; n < 4; ++n)
          acc[m][n] = __builtin_amdgcn_mfma_f32_16x16x32_f16(af[m], bf[n], acc[m][n], 0, 0, 0);
    }
    if (t < 17) {
      *reinterpret_cast<f16x8*>(&As[cur^1][srow][spart*16])     = cvt8(g0, g1);
      *reinterpret_cast<f16x8*>(&As[cur^1][srow][spart*16 + 8]) = cvt8(g2, g3);
    }
  }
#undef XP_LOAD
#pragma unroll
  for (int m = 0; m < 4; ++m)
#pragma unroll
    for (int n = 0; n < 4; ++n) {
      const int col = wcol + n*16 + lo;
      const float bb = b_nr[col];
#pragma unroll
      for (int r = 0; r < 4; ++r) {
        const int rl = m*16 + hi*4 + r;
        float v = acc[m][n][r] + bb;
        Xp[(arow0 + rl) * 256 + col] = v;
        Xpf[(arow0 + rl) * 256 + col] = (f16)v;
      }
    }
}

// ---------------------------------------------------------------------------
// Generic K=256 f16 MFMA GEMM: C[M][ldc] = A[M][256] @ Bp^T (+bias)
// grid (M/64, Ncolblocks); each block 64 rows x 256 cols (4 waves x 64).
// ---------------------------------------------------------------------------
__global__ __launch_bounds__(256) void f16gemm(
    const f16* __restrict__ A, const f16* __restrict__ Bp,
    const float* __restrict__ bias, float* __restrict__ C,
    int ldc, int Nvalid, int Npad)
{
  const int rb = blockIdx.x, cb = blockIdx.y;
  const int tid = threadIdx.x;
  const int wave = tid >> 6, l = tid & 63;
  const int lo = l & 15, hi = l >> 4;
  const int wcol = cb * 256 + wave * 64;
  __shared__ f16 As[64][264];
  f32x4 acc[4][4] = {};
  const size_t arow0 = (size_t)rb * 64;

#pragma unroll
  for (int i = 0; i < 8; ++i) {
    int idx = i * 256 + tid;
    int rr = idx >> 5, part = idx & 31;
    *reinterpret_cast<f16x8*>(&As[rr][part*8]) =
        *reinterpret_cast<const f16x8*>(A + (arow0 + rr)*256 + part*8);
  }
  __syncthreads();

  for (int t = 0; t < 4; ++t) {
#pragma unroll
    for (int ks = 0; ks < 2; ++ks) {
      f16x8 af[4], bf[4];
      const int kc = t*8 + ks*4 + hi;
#pragma unroll
      for (int m = 0; m < 4; ++m)
        af[m] = *reinterpret_cast<const f16x8*>(&As[m*16 + lo][t*64 + ks*32 + hi*8]);
#pragma unroll
      for (int n = 0; n < 4; ++n)
        bf[n] = *reinterpret_cast<const f16x8*>(Bp + ((size_t)kc*Npad + (wcol + n*16 + lo)) * 8);
#pragma unroll
      for (int m = 0; m < 4; ++m)
#pragma unroll
        for (int n = 0; n < 4; ++n)
          acc[m][n] = __builtin_amdgcn_mfma_f32_16x16x32_f16(af[m], bf[n], acc[m][n], 0, 0, 0);
    }
  }
#pragma unroll
  for (int m = 0; m < 4; ++m)
#pragma unroll
    for (int n = 0; n < 4; ++n) {
      const int col = wcol + n*16 + lo;
      if (col < Nvalid) {
        const float bb = bias ? bias[col] : 0.0f;
#pragma unroll
        for (int r = 0; r < 4; ++r)
          C[(arow0 + m*16 + hi*4 + r) * (size_t)ldc + col] = acc[m][n][r] + bb;
      }
    }
}

// ---------------------------------------------------------------------------
// Fused score-1 + Mpre
// ---------------------------------------------------------------------------
__global__ __launch_bounds__(256) void s1_mpre(
    const f16* __restrict__ E0h, const f16* __restrict__ Bl1,
    const f16* __restrict__ Bev, const float* __restrict__ bl1,
    const float* __restrict__ Wl2, const float* __restrict__ bl2,
    const float* __restrict__ XpH, const float* __restrict__ bm,
    float* __restrict__ S1, f16* __restrict__ Mpreh)
{
  const int blk = blockIdx.x;
  const int tid = threadIdx.x;
  const int wave = tid >> 6, l = tid & 63;
  const int lo = l & 15, hi = l >> 4;
  const int wcol = wave * 64;
  __shared__ f16 As[2][64][72];
  __shared__ float red[64][4];
  f32x4 accS[4][4] = {}, accM[4][4] = {};
  const size_t arow0 = (size_t)blk * 64;
  const int rr0 = tid >> 3, part = tid & 7;
  f16x8 ga, gb;

#define SM_LOAD(T)                                                            \
  { ga = *reinterpret_cast<const f16x8*>(E0h + (arow0 + rr0)*256 + (T)*64 + part*8);      \
    gb = *reinterpret_cast<const f16x8*>(E0h + (arow0 + rr0 + 32)*256 + (T)*64 + part*8); }
#define SM_WRITE(BUF)                                                         \
  { *reinterpret_cast<f16x8*>(&As[BUF][rr0][part*8]) = ga;                    \
    *reinterpret_cast<f16x8*>(&As[BUF][rr0 + 32][part*8]) = gb; }

  SM_LOAD(0); SM_WRITE(0);
  for (int t = 0; t < 4; ++t) {
    __syncthreads();
    if (t < 3) SM_LOAD(t + 1);
    const int cur = t & 1;
#pragma unroll
    for (int ks = 0; ks < 2; ++ks) {
      f16x8 af[4], bfS[4], bfM[4];
      const int kc = t*8 + ks*4 + hi;
#pragma unroll
      for (int m = 0; m < 4; ++m)
        af[m] = *reinterpret_cast<const f16x8*>(&As[cur][m*16 + lo][ks*32 + hi*8]);
#pragma unroll
      for (int n = 0; n < 4; ++n) {
        bfS[n] = *reinterpret_cast<const f16x8*>(Bl1 + ((size_t)kc*256 + (wcol + n*16 + lo)) * 8);
        bfM[n] = *reinterpret_cast<const f16x8*>(Bev + ((size_t)kc*256 + (wcol + n*16 + lo)) * 8);
      }
#pragma unroll
      for (int m = 0; m < 4; ++m)
#pragma unroll
        for (int n = 0; n < 4; ++n) {
          accS[m][n] = __builtin_amdgcn_mfma_f32_16x16x32_f16(af[m], bfS[n], accS[m][n], 0, 0, 0);
          accM[m][n] = __builtin_amdgcn_mfma_f32_16x16x32_f16(af[m], bfM[n], accM[m][n], 0, 0, 0);
        }
    }
    if (t < 3) SM_WRITE(cur ^ 1);
  }
#undef SM_LOAD
#undef SM_WRITE
#pragma unroll
  for (int m = 0; m < 4; ++m) {
#pragma unroll
    for (int r = 0; r < 4; ++r) {
      float p = 0.f;
#pragma unroll
      for (int n = 0; n < 4; ++n) {
        const int col = wcol + n*16 + lo;
        p += Wl2[col] * fmaxf(accS[m][n][r] + bl1[col], 0.0f);
      }
      p += __shfl_xor(p, 1); p += __shfl_xor(p, 2);
      p += __shfl_xor(p, 4); p += __shfl_xor(p, 8);
      if (lo == 0) red[m*16 + hi*4 + r][wave] = p;
    }
  }
  const int rxb = (blk >> 6) * 64;
#pragma unroll
  for (int m = 0; m < 4; ++m)
#pragma unroll
    for (int n = 0; n < 4; ++n) {
      const int col = wcol + n*16 + lo;
      const float bb = bm[col];
#pragma unroll
      for (int r = 0; r < 4; ++r) {
        const int rl = m*16 + hi*4 + r;
        float v = accM[m][n][r] + XpH[(size_t)(rxb + rl)*256 + col] + bb;
        Mpreh[(arow0 + rl)*256 + col] = (f16)fmaxf(v, 0.0f);
      }
    }
  __syncthreads();
  if (tid < 64)
    S1[arow0 + tid] = sigmoidf_(bl2[0] + red[tid][0] + red[tid][1] + red[tid][2] + red[tid][3]);
}

// ---------------------------------------------------------------------------
// Score pass 2 (transposed gather): adj = A2, S2 = sigmoid(A2)
// ---------------------------------------------------------------------------
__global__ __launch_bounds__(256) void attn2(
    const f16* __restrict__ Mpreh, const float* __restrict__ S1,
    const f16* __restrict__ Bl1, const float* __restrict__ bl1,
    const float* __restrict__ Wl2, const float* __restrict__ bl2,
    float* __restrict__ S2, float* __restrict__ adj)
{
  const int blk = blockIdx.x;
  const int b = blk >> 6, v = blk & 63;
  const int tid = threadIdx.x;
  const int wave = tid >> 6, l = tid & 63;
  const int lo = l & 15, hi = l >> 4;
  const int wcol = wave * 64;
  __shared__ f16 As[2][64][72];
  __shared__ float red[64][4];
  __shared__ float s1s[64];
  f32x4 acc[4][4] = {};
  const int rr0 = tid >> 3, part = tid & 7;
  const size_t pbase = (size_t)b * 4096 + v;
  f16x8 ga, gb;

  if (tid < 64) s1s[tid] = S1[pbase + (size_t)tid * 64];
  __syncthreads();

#define A2_LOAD(T)                                                              \
  { ga = *reinterpret_cast<const f16x8*>(Mpreh + (pbase + (size_t)rr0*64)*256 + (T)*64 + part*8);     \
    gb = *reinterpret_cast<const f16x8*>(Mpreh + (pbase + (size_t)(rr0+32)*64)*256 + (T)*64 + part*8); }
#define A2_WRITE(BUF)                                                           \
  { f16 sa = (f16)s1s[rr0], sb = (f16)s1s[rr0 + 32];                            \
    f16x8 ha = ga, hb = gb;                                                     \
    _Pragma("unroll") for (int j = 0; j < 8; ++j) { ha[j] *= sa; hb[j] *= sb; } \
    *reinterpret_cast<f16x8*>(&As[BUF][rr0][part*8]) = ha;                      \
    *reinterpret_cast<f16x8*>(&As[BUF][rr0 + 32][part*8]) = hb; }

  A2_LOAD(0); A2_WRITE(0);
  for (int t = 0; t < 4; ++t) {
    __syncthreads();
    if (t < 3) A2_LOAD(t + 1);
    const int cur = t & 1;
#pragma unroll
    for (int ks = 0; ks < 2; ++ks) {
      f16x8 af[4], bf[4];
      const int kc = t*8 + ks*4 + hi;
#pragma unroll
      for (int m = 0; m < 4; ++m)
        af[m] = *reinterpret_cast<const f16x8*>(&As[cur][m*16 + lo][ks*32 + hi*8]);
#pragma unroll
      for (int n = 0; n < 4; ++n)
        bf[n] = *reinterpret_cast<const f16x8*>(Bl1 + ((size_t)kc*256 + (wcol + n*16 + lo)) * 8);
#pragma unroll
      for (int m = 0; m < 4; ++m)
#pragma unroll
        for (int n = 0; n < 4; ++n)
          acc[m][n] = __builtin_amdgcn_mfma_f32_16x16x32_f16(af[m], bf[n], acc[m][n], 0, 0, 0);
    }
    if (t < 3) A2_WRITE(cur ^ 1);
  }
#undef A2_LOAD
#undef A2_WRITE
#pragma unroll
  for (int m = 0; m < 4; ++m) {
#pragma unroll
    for (int r = 0; r < 4; ++r) {
      float p = 0.f;
#pragma unroll
      for (int n = 0; n < 4; ++n) {
        const int col = wcol + n*16 + lo;
        p += Wl2[col] * fmaxf(acc[m][n][r] + bl1[col], 0.0f);
      }
      p += __shfl_xor(p, 1); p += __shfl_xor(p, 2);
      p += __shfl_xor(p, 4); p += __shfl_xor(p, 8);
      if (lo == 0) red[m*16 + hi*4 + r][wave] = p;
    }
  }
  __syncthreads();
  if (tid < 64) {
    float s = bl2[0] + red[tid][0] + red[tid][1] + red[tid][2] + red[tid][3];
    size_t oi = (size_t)b*4096 + v*64 + tid;
    adj[oi] = s;
    S2[oi] = sigmoidf_(s);
  }
}

// x[bv][c] = sum_w Mpre[bv*64+w][c] * S2[bv*64+w]  -> f16
__global__ __launch_bounds__(256) void msum_kernel(
    const f16* __restrict__ Mpre, const float* __restrict__ S2,
    f16* __restrict__ x)
{
  const int bv = blockIdx.x;
  const int c = threadIdx.x;
  float acc = 0.f;
#pragma unroll 8
  for (int w = 0; w < 64; ++w)
    acc += (float)Mpre[((size_t)bv * 64 + w) * 256 + c] * S2[bv * 64 + w];
  x[(size_t)bv * 256 + c] = (f16)acc;
}

// GRU elementwise: reads gi/gh (bias already applied), Xp fp32; writes hn f16
__global__ __launch_bounds__(256) void gru_ew(
    const float* __restrict__ gi, const float* __restrict__ gh,
    const float* __restrict__ Xp, f16* __restrict__ hnf)
{
  const int row = blockIdx.x, c = threadIdx.x;
  const float* gir = gi + (size_t)row * 768;
  const float* ghr = gh + (size_t)row * 768;
  float r = sigmoidf_(gir[c] + ghr[c]);
  float z = sigmoidf_(gir[256 + c] + ghr[256 + c]);
  float n = tanhf(gir[512 + c] + r * ghr[512 + c]);
  float h = Xp[(size_t)row * 256 + c];
  hnf[(size_t)row * 256 + c] = (f16)((1.0f - z) * n + z * h);
}

} // namespace

extern "C" void kernel_launch(void* const* d_in, const int* in_sizes, int n_in,
                              void* d_out, int out_size, void* d_ws, size_t ws_size,
                              hipStream_t stream)
{
  const float* ef   = (const float*)d_in[0];
  const float* nf   = (const float*)d_in[1];
  const float* W_er = (const float*)d_in[7];
  const float* b_er = (const float*)d_in[8];
  const float* W_nr = (const float*)d_in[9];
  const float* b_nr = (const float*)d_in[10];
  const float* Wl1  = (const float*)d_in[11];
  const float* bl1  = (const float*)d_in[12];
  const float* Wl2  = (const float*)d_in[13];
  const float* bl2  = (const float*)d_in[14];
  const float* Wm   = (const float*)d_in[15];
  const float* bm   = (const float*)d_in[16];
  const float* Wi   = (const float*)d_in[17];
  const float* bi   = (const float*)d_in[18];
  const float* Wh   = (const float*)d_in[19];
  const float* bh   = (const float*)d_in[20];
  const float* Wro  = (const float*)d_in[21];
  const float* bro  = (const float*)d_in[22];

  float* ws = (float*)d_ws;
  float* Xp    = ws + OFF_XP;
  f16*   Xpf   = (f16*)(ws + OFF_XPF);
  float* XpH   = ws + OFF_XPH;
  float* S1    = ws + OFF_S1;
  float* S2    = ws + OFF_S2;
  f16*   xf    = (f16*)(ws + OFF_XF);
  float* gi    = ws + OFF_GI;
  float* gh    = ws + OFF_GH;
  f16*   hnf   = (f16*)(ws + OFF_HNF);
  f16*   Wer8  = (f16*)(ws + OFF_WER8);
  f16*   Wnr8  = (f16*)(ws + OFF_WNR8);
  f16*   Wev8  = (f16*)(ws + OFF_WEV8);
  f16*   Whw8  = (f16*)(ws + OFF_WHW8);
  f16*   Wl18  = (f16*)(ws + OFF_WL18);
  f16*   Wi8   = (f16*)(ws + OFF_WI8);
  f16*   Wh8   = (f16*)(ws + OFF_WH8);
  f16*   Wro8  = (f16*)(ws + OFF_WRO8);
  f16*   E0h   = (f16*)(ws + OFF_E0H);
  f16*   Mpreh = (f16*)(ws + OFF_MPREH);
  float* adj    = (float*)d_out;
  float* labels = (float*)d_out + PAIRS;

  dim3 blk(256);

  cast_all<<<dim3(680), blk, 0, stream>>>(W_er, W_nr, Wm, Wl1, Wi, Wh, Wro,
                                          Wer8, Wnr8, Wev8, Whw8, Wl18, Wi8, Wh8, Wro8);
  gemm_xp<<<dim3(16), blk, 0, stream>>>(nf, Wnr8, b_nr, Xp, Xpf);
  f16gemm<<<dim3(16, 1), blk, 0, stream>>>(Xpf, Whw8, nullptr, XpH, 256, 256, 256);
  gemm_e0<<<dim3(PAIRS / 64), blk, 0, stream>>>(ef, Wer8, b_er, E0h);
  s1_mpre<<<dim3(PAIRS / 64), blk, 0, stream>>>(E0h, Wl18, Wev8, bl1, Wl2, bl2,
                                                XpH, bm, S1, Mpreh);
  attn2<<<dim3(PAIRS / 64), blk, 0, stream>>>(Mpreh, S1, Wl18, bl1, Wl2, bl2,
                                              S2, adj);
  msum_kernel<<<dim3(ROWS), blk, 0, stream>>>(Mpreh, S2, xf);
  f16gemm<<<dim3(16, 3), blk, 0, stream>>>(xf, Wi8, bi, gi, 768, 768, 768);
  f16gemm<<<dim3(16, 3), blk, 0, stream>>>(Xpf, Wh8, bh, gh, 768, 768, 768);
  gru_ew<<<dim3(ROWS), blk, 0, stream>>>(gi, gh, Xp, hnf);
  f16gemm<<<dim3(16, 3), blk, 0, stream>>>(hnf, Wro8, bro, labels, KC, KC, 768);
}